// Round 20
// baseline (115.739 us; speedup 1.0000x reference)
//
#include <hip/hip_runtime.h>
#include <hip/hip_bf16.h>

#define S_TOT 2720

typedef short bf16x8 __attribute__((ext_vector_type(8)));
typedef float f32x4 __attribute__((ext_vector_type(4)));

__device__ __forceinline__ float bf2f(short u) {
    return __uint_as_float(((unsigned int)(unsigned short)u) << 16);
}

// ---------------- prep: all weight transpose+cvt (393216) + down projection (131072)
// layout in ws: w1t[2][512][128] | w2t[2][128][512] | wqkvt[2][3][128][128] | wot[2][128][128]
__global__ void prep_kernel(const float* __restrict__ w1, const float* __restrict__ w2,
                            const float* __restrict__ wq, const float* __restrict__ wk,
                            const float* __restrict__ wv, const float* __restrict__ wo,
                            __hip_bfloat16* __restrict__ out,
                            const float* __restrict__ x, const float* __restrict__ wd,
                            const float* __restrict__ bd, float* __restrict__ t0) {
    int id = blockIdx.x * 256 + threadIdx.x;   // 524288 total
    if (id < 131072) {                         // w1t[l][j][k] = w1[l][k][j]
        int l = id >> 16, r = id & 65535;
        int j = r >> 7, k = r & 127;
        out[id] = __float2bfloat16(w1[l * 65536 + k * 512 + j]);
    } else if (id < 262144) {                  // w2t[l][d][j] = w2[l][j][d]
        int t = id - 131072;
        int l = t >> 16, r = t & 65535;
        int d = r >> 9, j = r & 511;
        out[id] = __float2bfloat16(w2[l * 65536 + j * 128 + d]);
    } else if (id < 360448) {                  // wqkvt[l][m][j][k] = W_m[l][k][j]
        int t = id - 262144;
        int l = t / 49152, r = t % 49152;
        int m = r >> 14, rr = r & 16383;
        int j = rr >> 7, k = rr & 127;
        const float* W = (m == 0) ? wq : (m == 1) ? wk : wv;
        out[id] = __float2bfloat16(W[l * 16384 + k * 128 + j]);
    } else if (id < 393216) {                  // wot[l][j][k] = wo[l][k][j]
        int t = id - 360448;
        int l = t >> 14, r = t & 16383;
        int j = r >> 7, k = r & 127;
        out[id] = __float2bfloat16(wo[l * 16384 + k * 128 + j]);
    } else {                                   // down projection
        int did = id - 393216;                 // 131072
        int c = did & 31;
        int r = did >> 5;
        const float* xr = x + (size_t)r * 128;
        float a0 = bd[c], a1 = 0.f, a2 = 0.f, a3 = 0.f;
#pragma unroll
        for (int k = 0; k < 128; k += 4) {
            a0 += xr[k]     * wd[(k)     * 32 + c];
            a1 += xr[k + 1] * wd[(k + 1) * 32 + c];
            a2 += xr[k + 2] * wd[(k + 2) * 32 + c];
            a3 += xr[k + 3] * wd[(k + 3) * 32 + c];
        }
        t0[did] = (a0 + a1) + (a2 + a3);
    }
}

// ---------------- conv (stride4,k4) + bias + BN + ELU
__global__ void conv_kernel(const float* __restrict__ in, float* __restrict__ pooled,
                            const float* __restrict__ cw, const float* __restrict__ cb,
                            const float* __restrict__ bg, const float* __restrict__ bb,
                            const float* __restrict__ bm, const float* __restrict__ bv,
                            int level, int in_bstride, int in_off, int Lout, int out_off,
                            int total) {
    int id = blockIdx.x * 256 + threadIdx.x;
    if (id >= total) return;
    int co = id & 31;
    int lo = (id >> 5) % Lout;
    int b  = id / (32 * Lout);
    const float* ib = in + (size_t)(b * in_bstride + in_off + lo * 4) * 32;
    const float* w  = cw + (size_t)(level * 32 + co) * 32 * 4;
    float acc0 = 0.f, acc1 = 0.f, acc2 = 0.f, acc3 = 0.f;
#pragma unroll
    for (int ci = 0; ci < 32; ++ci) {
        acc0 += ib[0 * 32 + ci] * w[ci * 4 + 0];
        acc1 += ib[1 * 32 + ci] * w[ci * 4 + 1];
        acc2 += ib[2 * 32 + ci] * w[ci * 4 + 2];
        acc3 += ib[3 * 32 + ci] * w[ci * 4 + 3];
    }
    float acc = ((acc0 + acc1) + (acc2 + acc3)) + cb[level * 32 + co];
    acc = (acc - bm[level * 32 + co]) * rsqrtf(bv[level * 32 + co] + 1e-5f)
          * bg[level * 32 + co] + bb[level * 32 + co];
    acc = acc > 0.f ? acc : expm1f(acc);
    pooled[(size_t)(b * 672 + out_off + lo) * 32 + co] = acc;
}

// ---------------- build h rows fused with LN0. wave per row.
__global__ void build_ln_kernel(const float* __restrict__ x, const float* __restrict__ pooled,
                                const float* __restrict__ w_up, const float* __restrict__ b_up,
                                const float* __restrict__ g, const float* __restrict__ bta,
                                float* __restrict__ h) {
    int wave = threadIdx.x >> 6;
    int lane = threadIdx.x & 63;
    int row = blockIdx.x * 4 + wave;          // 5440 rows
    int b = row / S_TOT, s = row % S_TOT;
    float v0, v1;
    if (s < 2048) {
        const float* xr = x + (size_t)(b * 2048 + s) * 128;
        v0 = xr[lane]; v1 = xr[lane + 64];
    } else {
        int p = s - 2048;
        const float* pr = pooled + (size_t)(b * 672 + p) * 32;
        float a0 = b_up[lane], a1 = b_up[lane + 64];
        float a2 = 0.f, a3 = 0.f;
#pragma unroll
        for (int k = 0; k < 32; k += 2) {
            float p0 = pr[k], p1 = pr[k + 1];
            a0 += p0 * w_up[k * 128 + lane];
            a1 += p0 * w_up[k * 128 + lane + 64];
            a2 += p1 * w_up[(k + 1) * 128 + lane];
            a3 += p1 * w_up[(k + 1) * 128 + lane + 64];
        }
        v0 = a0 + a2; v1 = a1 + a3;
    }
    float sum = v0 + v1;
#pragma unroll
    for (int off = 32; off; off >>= 1) sum += __shfl_xor(sum, off);
    float mu = sum * (1.f / 128.f);
    float d0 = v0 - mu, d1 = v1 - mu;
    float vs = d0 * d0 + d1 * d1;
#pragma unroll
    for (int off = 32; off; off >>= 1) vs += __shfl_xor(vs, off);
    float inv = rsqrtf(vs * (1.f / 128.f) + 1e-5f);
    h[(size_t)row * 128 + lane]      = d0 * inv * g[lane]      + bta[lane];
    h[(size_t)row * 128 + lane + 64] = d1 * inv * g[lane + 64] + bta[lane + 64];
}

// ---------------- MFMA QKV: 340 blocks x 16 rows, 4 waves x 6 col-tiles. BF16 outputs.
__global__ __launch_bounds__(256) void qkv_mfma_kernel(const float* __restrict__ H,
                                                       const __hip_bfloat16* __restrict__ wqkvt,
                                                       __hip_bfloat16* __restrict__ q,
                                                       __hip_bfloat16* __restrict__ k,
                                                       __hip_bfloat16* __restrict__ v) {
    __shared__ __hip_bfloat16 hsb[16][136];
    int tid = threadIdx.x;
    int r0 = blockIdx.x * 16;
    {
        int row = tid >> 4, c0 = (tid & 15) * 8;
        const float* src = &H[(size_t)(r0 + row) * 128 + c0];
        float4 x0 = *(const float4*)src;
        float4 x1 = *(const float4*)(src + 4);
        __hip_bfloat16* d = &hsb[row][c0];
        d[0] = __float2bfloat16(x0.x); d[1] = __float2bfloat16(x0.y);
        d[2] = __float2bfloat16(x0.z); d[3] = __float2bfloat16(x0.w);
        d[4] = __float2bfloat16(x1.x); d[5] = __float2bfloat16(x1.y);
        d[6] = __float2bfloat16(x1.z); d[7] = __float2bfloat16(x1.w);
    }
    __syncthreads();
    int lane = tid & 63, wv = tid >> 6;
    int l15 = lane & 15, grp = lane >> 4;
    bf16x8 afr[4];
#pragma unroll
    for (int ks = 0; ks < 4; ++ks)
        afr[ks] = *(const bf16x8*)&hsb[l15][ks * 32 + grp * 8];
    __hip_bfloat16* O[3] = {q, k, v};
#pragma unroll
    for (int t = 0; t < 6; ++t) {
        int gt = wv * 6 + t;
        int mat = gt >> 3, jj = gt & 7;
        int j0 = jj * 16;
        f32x4 acc = {0.f, 0.f, 0.f, 0.f};
        const __hip_bfloat16* wb = &wqkvt[(size_t)(mat * 128 + j0 + l15) * 128 + grp * 8];
#pragma unroll
        for (int ks = 0; ks < 4; ++ks) {
            bf16x8 bfr = *(const bf16x8*)&wb[ks * 32];
            acc = __builtin_amdgcn_mfma_f32_16x16x32_bf16(afr[ks], bfr, acc, 0, 0, 0);
        }
        __hip_bfloat16* Om = O[mat];
#pragma unroll
        for (int i = 0; i < 4; ++i)
            Om[(size_t)(r0 + grp * 4 + i) * 128 + j0 + l15] = __float2bfloat16(acc[i]);
    }
}

// ---------------- FUSED attn + o-proj + LN1 + FFN + LN2 per 16-row tile. 340 blocks.
__global__ __launch_bounds__(256) void attn_o_ffn_kernel(const __hip_bfloat16* __restrict__ Q,
                                                         const __hip_bfloat16* __restrict__ K,
                                                         const __hip_bfloat16* __restrict__ V,
                                                         const __hip_bfloat16* __restrict__ wot,
                                                         const float* __restrict__ g1,
                                                         const float* __restrict__ b1ta,
                                                         const __hip_bfloat16* __restrict__ w1t,
                                                         const float* __restrict__ b1,
                                                         const __hip_bfloat16* __restrict__ w2t,
                                                         const float* __restrict__ b2,
                                                         const float* __restrict__ g2,
                                                         const float* __restrict__ b2ta,
                                                         float* __restrict__ h) {
    __shared__ __hip_bfloat16 osb[16][136];   // attn output bf16, reused as LN1-out operand
    __shared__ __hip_bfloat16 pb[16][520];    // relu(f1) bf16
    __shared__ float partf[16][128];          // GEMM fp32 out
    __shared__ float h1s[16][128];            // LN1 output fp32 (FFN residual)
    int tid = threadIdx.x;
    int r0 = blockIdx.x * 16;
    // ---- Phase A: sparse pyramid attention for this tile's 16 rows
    {
        int rl = tid >> 4;                    // row in tile
        int hh = (tid >> 2) & 3;              // head
        int qd = tid & 3;                     // quarter (8 dims)
        int d0 = qd * 8;
        int row = r0 + rl;
        int b = row / S_TOT, i = row % S_TOT;
        int li, s;
        if (i < 2048)      { li = 0; s = 0;    }
        else if (i < 2560) { li = 1; s = 2048; }
        else if (i < 2688) { li = 2; s = 2560; }
        else               { li = 3; s = 2688; }
        int sz = (li == 0) ? 2048 : (li == 1) ? 512 : (li == 2) ? 128 : 32;
        int pstart = (li == 0) ? 2048 : (li == 1) ? 2560 : 2688;
        int cstart = (li == 1) ? 0 : (li == 2) ? 2048 : 2560;

        bf16x8 qv = *(const bf16x8*)(Q + (size_t)row * 128 + hh * 32 + d0);
        float qf[8];
#pragma unroll
        for (int e = 0; e < 8; ++e) qf[e] = bf2f(qv[e]);
        const float invt = 0.17677669529663687f;   // 1/sqrt(32)

        float sc[10];
        int   nj[10];
        bool  vl[10];
#pragma unroll
        for (int slot = 0; slot < 10; ++slot) {
            int j; bool valid;
            if (slot < 5)       { j = i - 2 + slot;                         valid = (j >= s) && (j < s + sz); }
            else if (slot == 5) { j = pstart + ((i - s) >> 2);              valid = (li < 3); }
            else                { j = cstart + ((i - s) << 2) + (slot - 6); valid = (li > 0); }
            nj[slot] = j; vl[slot] = valid;
            float dot = 0.f;
            if (valid) {
                bf16x8 kv = *(const bf16x8*)(K + (size_t)(b * S_TOT + j) * 128 + hh * 32 + d0);
#pragma unroll
                for (int e = 0; e < 8; ++e) dot += qf[e] * bf2f(kv[e]);
            }
            dot += __shfl_xor(dot, 1);
            dot += __shfl_xor(dot, 2);
            sc[slot] = valid ? dot * invt : -1e30f;
        }
        float mx = sc[0];
#pragma unroll
        for (int slot = 1; slot < 10; ++slot) mx = fmaxf(mx, sc[slot]);
        float ssum = 0.f;
#pragma unroll
        for (int slot = 0; slot < 10; ++slot) { sc[slot] = __expf(sc[slot] - mx); ssum += sc[slot]; }
        float rinv = 1.f / ssum;
        float oacc[8];
#pragma unroll
        for (int e = 0; e < 8; ++e) oacc[e] = 0.f;
#pragma unroll
        for (int slot = 0; slot < 10; ++slot) {
            if (vl[slot]) {
                float p = sc[slot] * rinv;
                bf16x8 vv = *(const bf16x8*)(V + (size_t)(b * S_TOT + nj[slot]) * 128 + hh * 32 + d0);
#pragma unroll
                for (int e = 0; e < 8; ++e) oacc[e] += p * bf2f(vv[e]);
            }
        }
        __hip_bfloat16* dst = &osb[rl][hh * 32 + d0];
#pragma unroll
        for (int e = 0; e < 8; ++e) dst[e] = __float2bfloat16(oacc[e]);
    }
    __syncthreads();
    int lane = tid & 63, wv = tid >> 6;
    int l15 = lane & 15, grp = lane >> 4;
    // ---- o-proj GEMM: 8 col-tiles over 4 waves (2 each)
    {
        bf16x8 afr[4];
#pragma unroll
        for (int ks = 0; ks < 4; ++ks)
            afr[ks] = *(const bf16x8*)&osb[l15][ks * 32 + grp * 8];
#pragma unroll
        for (int t = 0; t < 2; ++t) {
            int j0 = (wv * 2 + t) * 16;
            f32x4 acc = {0.f, 0.f, 0.f, 0.f};
            const __hip_bfloat16* wb = &wot[(size_t)(j0 + l15) * 128 + grp * 8];
#pragma unroll
            for (int ks = 0; ks < 4; ++ks) {
                bf16x8 bfr = *(const bf16x8*)&wb[ks * 32];
                acc = __builtin_amdgcn_mfma_f32_16x16x32_bf16(afr[ks], bfr, acc, 0, 0, 0);
            }
#pragma unroll
            for (int i = 0; i < 4; ++i)
                partf[grp * 4 + i][j0 + l15] = acc[i];
        }
    }
    __syncthreads();
    // ---- LN1: h1 = LN(o@wo + h_old); fp32 -> h1s, bf16 -> osb (FFN A operand)
    {
        int r = tid >> 4, d0 = (tid & 15) * 8;
        size_t row = (size_t)(r0 + r) * 128;
        float vv[8];
        float sum = 0.f;
#pragma unroll
        for (int i = 0; i < 8; ++i) {
            int d = d0 + i;
            vv[i] = partf[r][d] + h[row + d];
            sum += vv[i];
        }
#pragma unroll
        for (int off = 8; off; off >>= 1) sum += __shfl_xor(sum, off);
        float mu = sum * (1.f / 128.f);
        float vs = 0.f;
#pragma unroll
        for (int i = 0; i < 8; ++i) { vv[i] -= mu; vs += vv[i] * vv[i]; }
#pragma unroll
        for (int off = 8; off; off >>= 1) vs += __shfl_xor(vs, off);
        float inv = rsqrtf(vs * (1.f / 128.f) + 1e-6f);
        __hip_bfloat16* db = &osb[r][d0];
#pragma unroll
        for (int i = 0; i < 8; ++i) {
            float hv = vv[i] * inv * g1[d0 + i] + b1ta[d0 + i];
            h1s[r][d0 + i] = hv;
            db[i] = __float2bfloat16(hv);
        }
    }
    __syncthreads();
    // ---- FFN GEMM1 + ReLU -> pb
    {
        bf16x8 afr[4];
#pragma unroll
        for (int ks = 0; ks < 4; ++ks)
            afr[ks] = *(const bf16x8*)&osb[l15][ks * 32 + grp * 8];
#pragma unroll
        for (int t = 0; t < 8; ++t) {
            int j0 = (wv * 8 + t) * 16;
            f32x4 acc = {0.f, 0.f, 0.f, 0.f};
            const __hip_bfloat16* wb = &w1t[(size_t)(j0 + l15) * 128 + grp * 8];
#pragma unroll
            for (int ks = 0; ks < 4; ++ks) {
                bf16x8 bfr = *(const bf16x8*)&wb[ks * 32];
                acc = __builtin_amdgcn_mfma_f32_16x16x32_bf16(afr[ks], bfr, acc, 0, 0, 0);
            }
            float bv = b1[j0 + l15];
#pragma unroll
            for (int i = 0; i < 4; ++i)
                pb[grp * 4 + i][j0 + l15] = __float2bfloat16(fmaxf(acc[i] + bv, 0.f));
        }
    }
    __syncthreads();
    // ---- FFN GEMM2
    {
        f32x4 acc2a = {0.f, 0.f, 0.f, 0.f};
        f32x4 acc2b = {0.f, 0.f, 0.f, 0.f};
        const __hip_bfloat16* wb0 = &w2t[(size_t)(wv * 32 + l15) * 512 + grp * 8];
        const __hip_bfloat16* wb1 = &w2t[(size_t)(wv * 32 + 16 + l15) * 512 + grp * 8];
#pragma unroll
        for (int ks = 0; ks < 16; ++ks) {
            bf16x8 afr2 = *(const bf16x8*)&pb[l15][ks * 32 + grp * 8];
            bf16x8 b0 = *(const bf16x8*)&wb0[ks * 32];
            bf16x8 b1f = *(const bf16x8*)&wb1[ks * 32];
            acc2a = __builtin_amdgcn_mfma_f32_16x16x32_bf16(afr2, b0, acc2a, 0, 0, 0);
            acc2b = __builtin_amdgcn_mfma_f32_16x16x32_bf16(afr2, b1f, acc2b, 0, 0, 0);
        }
#pragma unroll
        for (int i = 0; i < 4; ++i) {
            partf[grp * 4 + i][wv * 32 + l15]      = acc2a[i];
            partf[grp * 4 + i][wv * 32 + 16 + l15] = acc2b[i];
        }
    }
    __syncthreads();
    // ---- final: + b2 + h1 -> LN2 -> h
    {
        int r = tid >> 4, d0 = (tid & 15) * 8;
        size_t row = (size_t)(r0 + r) * 128;
        float vv[8];
        float sum = 0.f;
#pragma unroll
        for (int i = 0; i < 8; ++i) {
            int d = d0 + i;
            vv[i] = partf[r][d] + b2[d] + h1s[r][d];
            sum += vv[i];
        }
#pragma unroll
        for (int off = 8; off; off >>= 1) sum += __shfl_xor(sum, off);
        float mu = sum * (1.f / 128.f);
        float vs = 0.f;
#pragma unroll
        for (int i = 0; i < 8; ++i) { vv[i] -= mu; vs += vv[i] * vv[i]; }
#pragma unroll
        for (int off = 8; off; off >>= 1) vs += __shfl_xor(vs, off);
        float inv = rsqrtf(vs * (1.f / 128.f) + 1e-6f);
#pragma unroll
        for (int i = 0; i < 8; ++i) vv[i] = vv[i] * inv * g2[d0 + i] + b2ta[d0 + i];
        *(float4*)&h[row + d0]     = make_float4(vv[0], vv[1], vv[2], vv[3]);
        *(float4*)&h[row + d0 + 4] = make_float4(vv[4], vv[5], vv[6], vv[7]);
    }
}

// ---------------- gather refer-points, float4
__global__ void gather_kernel(const float* __restrict__ H, const int* __restrict__ idx,
                              float* __restrict__ out) {
    int id = blockIdx.x * 256 + threadIdx.x;     // 524288 float4s
    int d4 = id & 31;
    int j = (id >> 5) & 3;
    int t = (id >> 7) & 2047;
    int b = id >> 18;
    int src = idx[t * 4 + j];
    ((float4*)out)[id] = *(const float4*)&H[((size_t)(b * S_TOT + src) * 128) + d4 * 4];
}

extern "C" void kernel_launch(void* const* d_in, const int* in_sizes, int n_in,
                              void* d_out, int out_size, void* d_ws, size_t ws_size,
                              hipStream_t stream) {
    (void)in_sizes; (void)n_in; (void)out_size; (void)ws_size;
    const float* x       = (const float*)d_in[0];
    const float* w_down  = (const float*)d_in[1];
    const float* b_down  = (const float*)d_in[2];
    const float* conv_w  = (const float*)d_in[3];
    const float* conv_b  = (const float*)d_in[4];
    const float* bn_g    = (const float*)d_in[5];
    const float* bn_b    = (const float*)d_in[6];
    const float* bn_m    = (const float*)d_in[7];
    const float* bn_v    = (const float*)d_in[8];
    const float* w_up    = (const float*)d_in[9];
    const float* b_up    = (const float*)d_in[10];
    const float* ln0_g   = (const float*)d_in[11];
    const float* ln0_b   = (const float*)d_in[12];
    const float* wq      = (const float*)d_in[13];
    const float* wk      = (const float*)d_in[14];
    const float* wv      = (const float*)d_in[15];
    const float* wo      = (const float*)d_in[16];
    const float* ln1_g   = (const float*)d_in[17];
    const float* ln1_b   = (const float*)d_in[18];
    const float* ffn_w1  = (const float*)d_in[19];
    const float* ffn_b1  = (const float*)d_in[20];
    const float* ffn_w2  = (const float*)d_in[21];
    const float* ffn_b2  = (const float*)d_in[22];
    const float* ln2_g   = (const float*)d_in[23];
    const float* ln2_b   = (const float*)d_in[24];
    const int* indexes   = (const int*)d_in[26];

    float* ws = (float*)d_ws;
    float* t0     = ws;               // 131072
    float* pooled = ws + 131072;      // 43008
    float* h      = ws + 174080;      // 696320
    __hip_bfloat16* qb = (__hip_bfloat16*)(ws + 870400);   // 696320 bf16 = 348160 floats
    __hip_bfloat16* kb = (__hip_bfloat16*)(ws + 1218560);
    __hip_bfloat16* vb = (__hip_bfloat16*)(ws + 1566720);
    __hip_bfloat16* wb_all = (__hip_bfloat16*)(ws + 1914880); // 393216 bf16
    __hip_bfloat16* w1t   = wb_all;            // [2][512][128]
    __hip_bfloat16* w2t   = wb_all + 131072;   // [2][128][512]
    __hip_bfloat16* wqkvt = wb_all + 262144;   // [2][3][128][128]
    __hip_bfloat16* wot   = wb_all + 360448;   // [2][128][128]

    prep_kernel<<<2048, 256, 0, stream>>>(ffn_w1, ffn_w2, wq, wk, wv, wo, wb_all,
                                          x, w_down, b_down, t0);
    conv_kernel<<<128, 256, 0, stream>>>(t0, pooled, conv_w, conv_b, bn_g, bn_b, bn_m, bn_v,
                                         0, 2048, 0, 512, 0, 32768);
    conv_kernel<<<32, 256, 0, stream>>>(pooled, pooled, conv_w, conv_b, bn_g, bn_b, bn_m, bn_v,
                                        1, 672, 0, 128, 512, 8192);
    conv_kernel<<<8, 256, 0, stream>>>(pooled, pooled, conv_w, conv_b, bn_g, bn_b, bn_m, bn_v,
                                       2, 672, 512, 32, 640, 2048);
    build_ln_kernel<<<1360, 256, 0, stream>>>(x, pooled, w_up, b_up, ln0_g, ln0_b, h);

    for (int l = 0; l < 2; ++l) {
        qkv_mfma_kernel<<<340, 256, 0, stream>>>(h, wqkvt + l * 49152, qb, kb, vb);
        attn_o_ffn_kernel<<<340, 256, 0, stream>>>(qb, kb, vb, wot + l * 16384,
                                                   ln1_g + l * 128, ln1_b + l * 128,
                                                   w1t + l * 65536, ffn_b1 + l * 512,
                                                   w2t + l * 65536, ffn_b2 + l * 128,
                                                   ln2_g + l * 128, ln2_b + l * 128, h);
    }
    gather_kernel<<<2048, 256, 0, stream>>>(h, indexes, (float*)d_out);
}